// Round 3
// baseline (1634.697 us; speedup 1.0000x reference)
//
#include <hip/hip_runtime.h>

#define BB 16
#define NN 8192
#define SS 512
#define N3 (3 * NN)  // 24576 elements per batch per tensor

typedef unsigned short u16;
typedef unsigned int u32;
typedef unsigned long long u64;

// ---------------------------------------------------------------------------
// K1: farthest point sampling, fp32, bit-exact vs numpy. One 1024-thr block
// per batch; 8 points/thread in registers. Distance ((x-c)^2+(y-c)^2)+(z-c)^2
// with rn ops (no FMA contraction); argmax tie-break = lowest index
// (np.argmax first-max). Center broadcast: owning thread writes its registers
// to a 3-float LDS slot. Writes keypoints [B,3,S] (exact fp32 copies).
// ---------------------------------------------------------------------------
__global__ __launch_bounds__(1024) void k_fps(const float* __restrict__ xyz,
                                              float* __restrict__ out_kp) {
  __shared__ int sIdx[SS];
  __shared__ float rv[16];
  __shared__ int ri[16];
  __shared__ int sFar;
  __shared__ float sCtr[3];
  int b = blockIdx.x, t = threadIdx.x;
  const float* base = xyz + b * N3;
  float px[8], py[8], pz[8], dmin[8];
#pragma unroll
  for (int k = 0; k < 8; ++k) {
    int n = k * 1024 + t;  // coalesced
    px[k] = base[n];
    py[k] = base[NN + n];
    pz[k] = base[2 * NN + n];
    dmin[k] = 1e10f;
  }
  if (t == 0) {
    sFar = 0;
    sCtr[0] = base[0];
    sCtr[1] = base[NN];
    sCtr[2] = base[2 * NN];
  }
  __syncthreads();
  int lane = t & 63, w = t >> 6;
  for (int it = 0; it < SS; ++it) {
    if (t == 0) sIdx[it] = sFar;  // scan emits carry BEFORE update: idx[0]=0
    float cx = sCtr[0], cy = sCtr[1], cz = sCtr[2];
    float v = -1.0f;
    int vi = 0;
#pragma unroll
    for (int k = 0; k < 8; ++k) {
      float dx = __fsub_rn(px[k], cx);
      float dy = __fsub_rn(py[k], cy);
      float dz = __fsub_rn(pz[k], cz);
      float d = __fadd_rn(__fadd_rn(__fmul_rn(dx, dx), __fmul_rn(dy, dy)), __fmul_rn(dz, dz));
      float nd = fminf(dmin[k], d);
      dmin[k] = nd;
      if (nd > v) { v = nd; vi = k * 1024 + t; }  // strict >: first (lowest k) wins
    }
#pragma unroll
    for (int off = 1; off < 64; off <<= 1) {
      float ov = __shfl_xor(v, off, 64);
      int oi = __shfl_xor(vi, off, 64);
      if (ov > v || (ov == v && oi < vi)) { v = ov; vi = oi; }
    }
    if (lane == 0) { rv[w] = v; ri[w] = vi; }
    __syncthreads();  // A: rv/ri ready; also orders sCtr reads before overwrite
    if (w == 0) {
      float v2 = (lane < 16) ? rv[lane] : -1.0f;
      int i2 = (lane < 16) ? ri[lane] : 0x7fffffff;
#pragma unroll
      for (int off = 1; off < 16; off <<= 1) {
        float ov = __shfl_xor(v2, off, 64);
        int oi = __shfl_xor(i2, off, 64);
        if (ov > v2 || (ov == v2 && oi < i2)) { v2 = ov; i2 = oi; }
      }
      if (lane == 0) sFar = i2;
    }
    __syncthreads();  // B: sFar ready
    int nf = sFar;
    if ((nf & 1023) == t) {  // owner pushes exact fp32 center coords
      int k = nf >> 10;
      sCtr[0] = px[k];
      sCtr[1] = py[k];
      sCtr[2] = pz[k];
    }
    __syncthreads();  // C: center ready for next iteration
  }
  if (t < SS) {
    int id = sIdx[t];
    out_kp[b * 1536 + t] = base[id];  // exact fp32 copies
    out_kp[b * 1536 + SS + t] = base[NN + id];
    out_kp[b * 1536 + 2 * SS + t] = base[2 * NN + id];
  }
}

// ---------------------------------------------------------------------------
// K2: per (b,s) row, sorted top-24 nearest (dist asc, idx asc) — prefixes give
// K=8/16/24 and base K=16 (lax.top_k stable tie-break). One wave per row,
// 4 rows/block; points read from global (L2-resident, 96 KB/batch).
// d = (|a|^2+|q|^2) - 2*dot, all rn ops, matching the numpy expression tree.
// ---------------------------------------------------------------------------
__global__ __launch_bounds__(256) void k_knn(const float* __restrict__ xyz,
                                             const float* __restrict__ kp,
                                             u16* __restrict__ knn) {
  int t = threadIdx.x;
  int row = blockIdx.x * 4 + (t >> 6);
  int lane = t & 63;
  int b = row >> 9, s = row & (SS - 1);
  const float* base = xyz + b * N3;
  float ax = kp[b * 1536 + s];
  float ay = kp[b * 1536 + SS + s];
  float az = kp[b * 1536 + 2 * SS + s];
  float aw = __fadd_rn(__fadd_rn(__fmul_rn(ax, ax), __fmul_rn(ay, ay)), __fmul_rn(az, az));
  u64 arr[24];
#pragma unroll
  for (int i = 0; i < 24; ++i) arr[i] = ~0ull;
  for (int c = 0; c < 128; ++c) {
    int n = c * 64 + lane;
    float qx = base[n], qy = base[NN + n], qz = base[2 * NN + n];
    float qw = __fadd_rn(__fadd_rn(__fmul_rn(qx, qx), __fmul_rn(qy, qy)), __fmul_rn(qz, qz));
    float dot = __fadd_rn(__fadd_rn(__fmul_rn(ax, qx), __fmul_rn(ay, qy)), __fmul_rn(az, qz));
    float d = __fsub_rn(__fadd_rn(aw, qw), __fmul_rn(2.0f, dot));
    u32 ub = __float_as_uint(d);
    ub ^= (ub & 0x80000000u) ? 0xFFFFFFFFu : 0x80000000u;  // order-preserving map
    u64 key = ((u64)ub << 32) | (u32)n;
    if (key < arr[23]) {  // branchless descending insertion (arr sorted asc)
#pragma unroll
      for (int i = 23; i >= 1; --i) {
        u64 am = arr[i - 1];
        arr[i] = (am > key) ? am : ((arr[i] > key) ? key : arr[i]);
      }
      if (arr[0] > key) arr[0] = key;
    }
  }
  // merge 64 sorted lists: 24 x (wave-min of heads, winner pops). keys unique.
  u64 mine = 0;
  for (int it = 0; it < 24; ++it) {
    u64 m = arr[0];
#pragma unroll
    for (int off = 1; off < 64; off <<= 1) {
      u64 o = __shfl_xor(m, off, 64);
      m = (o < m) ? o : m;
    }
    if (lane == it) mine = m;
    if (arr[0] == m) {
#pragma unroll
      for (int i = 0; i < 23; ++i) arr[i] = arr[i + 1];
      arr[23] = ~0ull;
    }
  }
  if (lane < 24) knn[row * 24 + lane] = (u16)(mine & 0xFFFFu);
}

// ---------------------------------------------------------------------------
// K3: base SA MLP. feat[16][6] = [rel_xyz | pts]; 6->64 relu -> 64->128; max
// over K=16. 8 rows/block; W2 rows in registers (32 f32/thread, 2 thr/chan).
// ---------------------------------------------------------------------------
__global__ __launch_bounds__(256) void k_base(
    const float* __restrict__ xyz, const float* __restrict__ pts,
    const float* __restrict__ kp, const u16* __restrict__ knn,
    const float* __restrict__ W1, const float* __restrict__ b1,
    const float* __restrict__ W2, const float* __restrict__ b2,
    float* __restrict__ out) {
  __shared__ float sW1T[6 * 64];   // [c][o]
  __shared__ float sb1[64], sb2[128];
  __shared__ float sfeat[16 * 6];  // [k][c]
  __shared__ float sh1[16 * 64];   // [k][o]
  __shared__ float spart[2][16][128];
  int t = threadIdx.x;
  int b = blockIdx.x >> 6, s0 = (blockIdx.x & 63) * 8;
  for (int i = t; i < 384; i += 256) {
    int o = i / 6, c = i - o * 6;
    sW1T[c * 64 + o] = W1[i];
  }
  if (t < 64) sb1[t] = b1[t];
  if (t < 128) sb2[t] = b2[t];
  int p = t & 127, h = t >> 7;
  float w[32];
#pragma unroll
  for (int j = 0; j < 32; ++j) w[j] = W2[p * 64 + h * 32 + j];
  __syncthreads();
  for (int r = 0; r < 8; ++r) {
    int s = s0 + r, row = b * SS + s;
    if (t < 128) {
      int k = t >> 3, c = t & 7;
      if (c < 6) {
        int id = knn[row * 24 + k];  // first 16 of sorted top-24 = base KNN
        float val;
        if (c < 3) {
          float ac = kp[b * 1536 + c * SS + s];
          val = __fsub_rn(xyz[b * N3 + c * NN + id], ac);
        } else {
          val = pts[b * N3 + (c - 3) * NN + id];
        }
        sfeat[k * 6 + c] = val;
      }
    }
    __syncthreads();
#pragma unroll
    for (int m = 0; m < 4; ++m) {
      int u = m * 256 + t;
      int k = u >> 6, o = u & 63;  // o == lane -> sW1T reads conflict-free
      float acc = 0.f;
#pragma unroll
      for (int c = 0; c < 6; ++c) acc = fmaf(sfeat[k * 6 + c], sW1T[c * 64 + o], acc);
      acc += sb1[o];
      sh1[k * 64 + o] = fmaxf(acc, 0.f);
    }
    __syncthreads();
#pragma unroll
    for (int k = 0; k < 16; ++k) {
      const float* hr = &sh1[k * 64 + h * 32];  // broadcast reads
      float acc = 0.f;
#pragma unroll
      for (int j = 0; j < 32; ++j) acc = fmaf(hr[j], w[j], acc);
      spart[h][k][p] = acc;
    }
    __syncthreads();
    if (t < 128) {
      float best = -1e30f;
#pragma unroll
      for (int k = 0; k < 16; ++k) best = fmaxf(best, spart[0][k][t] + spart[1][k][t]);
      out[24576 + b * 262144 + t * 512 + s] = best + sb2[t];
    }
    __syncthreads();
  }
}

// ---------------------------------------------------------------------------
// K4: multi-scale MLPs, scale = blockIdx.y, K = 8*(scale+1), rel-xyz only.
// Output channels 128*(scale+1) .. +128.
// ---------------------------------------------------------------------------
__global__ __launch_bounds__(256) void k_ms(
    const float* __restrict__ xyz, const float* __restrict__ kp,
    const u16* __restrict__ knn, const float* __restrict__ msW1,
    const float* __restrict__ msb1, const float* __restrict__ msW2,
    const float* __restrict__ msb2, float* __restrict__ out) {
  int scale = blockIdx.y;
  int kk = 8 * (scale + 1);
  __shared__ float sW1T[3 * 64];
  __shared__ float sb1[64], sb2[128];
  __shared__ float sfeat[24 * 3];
  __shared__ float sh1[24 * 64];
  __shared__ float spart[2][24][128];
  int t = threadIdx.x;
  int b = blockIdx.x >> 6, s0 = (blockIdx.x & 63) * 8;
  const float* W1s = msW1 + scale * 192;
  for (int i = t; i < 192; i += 256) {
    int o = i / 3, c = i - o * 3;
    sW1T[c * 64 + o] = W1s[i];
  }
  if (t < 64) sb1[t] = msb1[scale * 64 + t];
  if (t < 128) sb2[t] = msb2[scale * 128 + t];
  int p = t & 127, h = t >> 7;
  float w[32];
#pragma unroll
  for (int j = 0; j < 32; ++j) w[j] = msW2[scale * 8192 + p * 64 + h * 32 + j];
  __syncthreads();
  int co = 128 * (scale + 1);
  for (int r = 0; r < 8; ++r) {
    int s = s0 + r, row = b * SS + s;
    if (t < 96) {
      int k = t >> 2, c = t & 3;
      if (c < 3 && k < kk) {
        int id = knn[row * 24 + k];
        float ac = kp[b * 1536 + c * SS + s];
        sfeat[k * 3 + c] = __fsub_rn(xyz[b * N3 + c * NN + id], ac);
      }
    }
    __syncthreads();
    for (int u = t; u < kk * 64; u += 256) {
      int k = u >> 6, o = u & 63;
      float acc = fmaf(sfeat[k * 3 + 0], sW1T[o], 0.f);
      acc = fmaf(sfeat[k * 3 + 1], sW1T[64 + o], acc);
      acc = fmaf(sfeat[k * 3 + 2], sW1T[128 + o], acc);
      acc += sb1[o];
      sh1[k * 64 + o] = fmaxf(acc, 0.f);
    }
    __syncthreads();
    for (int k = 0; k < kk; ++k) {
      const float* hr = &sh1[k * 64 + h * 32];
      float acc = 0.f;
#pragma unroll
      for (int j = 0; j < 32; ++j) acc = fmaf(hr[j], w[j], acc);
      spart[h][k][p] = acc;
    }
    __syncthreads();
    if (t < 128) {
      float best = -1e30f;
      for (int k = 0; k < kk; ++k) best = fmaxf(best, spart[0][k][t] + spart[1][k][t]);
      out[24576 + b * 262144 + (co + t) * 512 + s] = best + sb2[t];
    }
    __syncthreads();
  }
}

// ---------------------------------------------------------------------------
extern "C" void kernel_launch(void* const* d_in, const int* in_sizes, int n_in,
                              void* d_out, int out_size, void* d_ws, size_t ws_size,
                              hipStream_t stream) {
  const float* xyz = (const float*)d_in[0];    // l0_xyz  [B,3,N] f32
  const float* pts = (const float*)d_in[1];    // l0_points
  const float* sa_W1 = (const float*)d_in[2];  // [64,6]
  const float* sa_b1 = (const float*)d_in[3];  // [64]
  const float* sa_W2 = (const float*)d_in[4];  // [128,64]
  const float* sa_b2 = (const float*)d_in[5];  // [128]
  const float* ms_W1 = (const float*)d_in[6];  // [3,64,3]
  const float* ms_b1 = (const float*)d_in[7];  // [3,64]
  const float* ms_W2 = (const float*)d_in[8];  // [3,128,64]
  const float* ms_b2 = (const float*)d_in[9];  // [3,128]
  float* out = (float*)d_out;
  const float* kp = (const float*)d_out;  // keypoints written by k_fps

  // workspace: knn u16[B*S*24] = 384 KB
  u16* knn = (u16*)d_ws;

  k_fps<<<BB, 1024, 0, stream>>>(xyz, out);
  k_knn<<<(BB * SS) / 4, 256, 0, stream>>>(xyz, kp, knn);
  k_base<<<BB * 64, 256, 0, stream>>>(xyz, pts, kp, knn, sa_W1, sa_b1, sa_W2, sa_b2, out);
  k_ms<<<dim3(BB * 64, 3), 256, 0, stream>>>(xyz, kp, knn, ms_W1, ms_b1, ms_W2, ms_b2, out);
}